// Round 4
// baseline (330.075 us; speedup 1.0000x reference)
//
#include <hip/hip_runtime.h>
#include <hip/hip_bf16.h>

// LoRA-factored 3x3 conv. out fp32 (proven R3: WRITE_SIZE==4B/elem).
// x: [16,128,56,56], A: [256,16], B: [16,1152] -> out: [16,256,56,56]
// Input dtypes detected per tensor at runtime (proven working in R3).
// Block = one image row (h) of one batch; 4 waves r-split stage1, o-split stage2.
// x staged in LDS fp32 with zero halo -> no per-tap bounds checks.

#define Bn 16
#define Cc 128
#define Hh 56
#define Ww 56
#define Ll (Hh * Ww)      // 3136
#define Rr 16
#define Oo 256
#define KF (Cc * 9)       // 1152
#define CG 4              // channels staged per group
#define LROW 66           // LDS row stride: cols -1..64 (zero-padded), no bank issues

__device__ __forceinline__ float bf16_bits(unsigned short u) {
    return __uint_as_float(((unsigned)u) << 16);
}

template<bool BF>
__device__ __forceinline__ float ld(const void* __restrict__ p, size_t i) {
    if constexpr (BF) return bf16_bits(((const unsigned short*)p)[i]);
    else              return ((const float*)p)[i];
}

// bf16-packed: bits14..7 of each word = bf16 exponent (~[96,144]) -> 32/32 hits.
// fp32: those bits are uniform mantissa -> ~6/32 hits. Threshold 20.
__device__ __forceinline__ bool detect_bf16(const void* __restrict__ p) {
    const unsigned* w = (const unsigned*)p;
    int c = 0;
#pragma unroll
    for (int i = 0; i < 32; ++i) {
        const unsigned e = (w[i] >> 7) & 0xFFu;
        c += (e >= 96u && e <= 144u) ? 1 : 0;
    }
    return c >= 20;
}

template<bool XB, bool AB, bool BB>
__device__ __forceinline__ void body(const void* __restrict__ x,
                                     const void* __restrict__ A,
                                     const void* __restrict__ Bm,
                                     float* __restrict__ out,
                                     float (* __restrict__ xs)[3][LROW],  // [CG][3][66]
                                     float (* __restrict__ part)[64])     // [16][64]
{
    const int tid  = threadIdx.x;
    const int lane = tid & 63;        // w coordinate (active if < 56)
    const int rg   = tid >> 6;        // wave 0..3
    const int h    = blockIdx.x;      // image row
    const int b    = blockIdx.y;      // batch
    const int r0   = rg * 4;

    float acc[4] = {0.f, 0.f, 0.f, 0.f};
    const size_t xbase = (size_t)b * Cc * Ll;

    for (int c0 = 0; c0 < Cc; c0 += CG) {
        __syncthreads();   // previous group's readers done before overwrite
        // ---- stage CG channels x rows(h-1..h+1) x cols(-1..64) as fp32, zero-padded
        for (int i = tid; i < CG * 3 * LROW; i += 256) {
            const int cc  = i / (3 * LROW);
            const int rem = i - cc * (3 * LROW);
            const int rr  = rem / LROW;          // 0..2 -> h-1..h+1
            const int col = rem - rr * LROW;     // 0..65 -> w = col-1
            const int hh  = h + rr - 1;
            const int ww  = col - 1;
            float v = 0.f;
            if (hh >= 0 && hh < Hh && ww >= 0 && ww < Ww)
                v = ld<XB>(x, xbase + (size_t)(c0 + cc) * Ll + (size_t)(hh * Ww + ww));
            ((float*)xs)[i] = v;
        }
        __syncthreads();
        // ---- compute: per channel, 9 LDS taps (stride-1) + 36 FMA (4 ranks)
#pragma unroll
        for (int cc = 0; cc < CG; ++cc) {
            const int c = c0 + cc;
            float t[9];
#pragma unroll
            for (int dh = 0; dh < 3; ++dh)
#pragma unroll
                for (int dw = 0; dw < 3; ++dw)
                    t[dh * 3 + dw] = xs[cc][dh][lane + dw];   // col = (w+dw-1)+1
#pragma unroll
            for (int j = 0; j < 4; ++j) {
                const size_t bo = (size_t)(r0 + j) * KF + (size_t)c * 9;  // wave-uniform
                float s = acc[j];
#pragma unroll
                for (int i = 0; i < 9; ++i) s += ld<BB>(Bm, bo + i) * t[i];
                acc[j] = s;
            }
        }
    }

    // ---- exchange partial ranks across waves (stride-1, conflict-free)
#pragma unroll
    for (int j = 0; j < 4; ++j) part[r0 + j][lane] = acc[j];
    __syncthreads();
    float tv[Rr];
#pragma unroll
    for (int r = 0; r < Rr; ++r) tv[r] = part[r][lane];

    // ---- stage 2: wave rg emits output channels rg*64..rg*64+63
    const bool active = (lane < Ww);
    const size_t obase = (size_t)b * Oo * Ll + (size_t)(h * Ww) + (size_t)lane;
#pragma unroll 4
    for (int oo = 0; oo < 64; ++oo) {
        const int o = rg * 64 + oo;
        float s = 0.f;
#pragma unroll
        for (int r = 0; r < Rr; ++r) s += ld<AB>(A, (size_t)o * Rr + r) * tv[r];
        if (active) out[obase + (size_t)o * Ll] = s;   // coalesced fp32
    }
}

__global__ __launch_bounds__(256) void fused_kernel(
    const void* __restrict__ x,
    const void* __restrict__ A,
    const void* __restrict__ Bm,
    float* __restrict__ out)
{
    __shared__ float xs[CG][3][LROW];   // 3.1 KB
    __shared__ float part[Rr][64];      // 4 KB

    const bool xb = detect_bf16(x);
    const bool ab = detect_bf16(A);
    const bool bb = detect_bf16(Bm);

    if (xb) {
        if (ab) { if (bb) body<true , true , true >(x, A, Bm, out, xs, part);
                  else    body<true , true , false>(x, A, Bm, out, xs, part); }
        else    { if (bb) body<true , false, true >(x, A, Bm, out, xs, part);
                  else    body<true , false, false>(x, A, Bm, out, xs, part); }
    } else {
        if (ab) { if (bb) body<false, true , true >(x, A, Bm, out, xs, part);
                  else    body<false, true , false>(x, A, Bm, out, xs, part); }
        else    { if (bb) body<false, false, true >(x, A, Bm, out, xs, part);
                  else    body<false, false, false>(x, A, Bm, out, xs, part); }
    }
}

extern "C" void kernel_launch(void* const* d_in, const int* in_sizes, int n_in,
                              void* d_out, int out_size, void* d_ws, size_t ws_size,
                              hipStream_t stream) {
    const void* x  = d_in[0];
    const void* A  = d_in[1];
    const void* Bm = d_in[2];
    for (int i = 0; i < n_in && i < 3; ++i) {
        const int s = in_sizes[i];
        if      (s == Bn * Cc * Ll) x  = d_in[i];
        else if (s == Oo * Rr)      A  = d_in[i];
        else if (s == Rr * KF)      Bm = d_in[i];
    }
    float* out = (float*)d_out;

    fused_kernel<<<dim3(Hh, Bn), 256, 0, stream>>>(x, A, Bm, out);
}

// Round 5
// 130.847 us; speedup vs baseline: 2.5226x; 2.5226x over previous
//
#include <hip/hip_runtime.h>
#include <hip/hip_bf16.h>

// LoRA-factored 3x3 conv. out fp32 (proven R3). Input dtypes runtime-detected.
// x: [16,128,56,56], A: [256,16], B: [16,1152] -> out: [16,256,56,56]
// R4 lesson: bottleneck is wave starvation (1-3 waves/SIMD) + barrier-exposed
// latency, NOT x-load locality. This round: 1024-thr blocks (16 waves), 2
// blocks/CU = 100% occupancy, 2 barriers total, B via scalar loads from a
// pre-transposed fp32 copy in d_ws.

#define Bn 16
#define Cc 128
#define Hh 56
#define Ww 56
#define Ll (Hh * Ww)      // 3136
#define Rr 16
#define Oo 256
#define KF (Cc * 9)       // 1152

__device__ __forceinline__ float bf16_bits(unsigned short u) {
    return __uint_as_float(((unsigned)u) << 16);
}

template<bool BF>
__device__ __forceinline__ float ld(const void* __restrict__ p, size_t i) {
    if constexpr (BF) return bf16_bits(((const unsigned short*)p)[i]);
    else              return ((const float*)p)[i];
}

// bf16-packed: bits14..7 of each dword = a bf16 exponent (~[96,144]) -> 32/32.
// fp32: uniform mantissa bits -> ~6/32. Threshold 20. (Proven R3.)
__device__ __forceinline__ bool detect_bf16(const void* __restrict__ p) {
    const unsigned* w = (const unsigned*)p;
    int c = 0;
#pragma unroll
    for (int i = 0; i < 32; ++i) {
        const unsigned e = (w[i] >> 7) & 0xFFu;
        c += (e >= 96u && e <= 144u) ? 1 : 0;
    }
    return c >= 20;
}

// ---- prep: Bt[k][r] = B[r][k] as fp32 (k = c*9+i), Afp[o][r] = A[o][r] fp32.
__global__ __launch_bounds__(256) void prep_kernel(
    const void* __restrict__ A, const void* __restrict__ Bm,
    float* __restrict__ Bt, float* __restrict__ Afp)
{
    const bool ab = detect_bf16(A);
    const bool bb = detect_bf16(Bm);
    const int i = blockIdx.x * 256 + threadIdx.x;
    if (i < KF * Rr) {
        const int k = i >> 4, r = i & 15;
        Bt[i] = bb ? bf16_bits(((const unsigned short*)Bm)[r * KF + k])
                   : ((const float*)Bm)[r * KF + k];
    }
    if (i < Oo * Rr) {
        Afp[i] = ab ? bf16_bits(((const unsigned short*)A)[i])
                    : ((const float*)A)[i];
    }
}

// ---- main: one block = one (b, h) row. 16 waves = 8 channel-slices x 2 rank-halves.
template<bool XB>
__device__ __forceinline__ void main_body(
    const void* __restrict__ x,
    const float* __restrict__ Bt,
    const float* __restrict__ Afp,
    float* __restrict__ out,
    float (* __restrict__ part)[Rr][64],   // [8][16][64]
    float (* __restrict__ tmp2)[17])       // [64][17]
{
    const int tid  = threadIdx.x;
    const int lane = tid & 63;                                  // w coordinate
    const int wv   = __builtin_amdgcn_readfirstlane(tid >> 6);  // wave 0..15 (SGPR)
    const int cs   = wv & 7;    // channel slice: channels cs*16 .. +16
    const int rh   = wv >> 3;   // rank half: ranks rh*8 .. +8
    const int h    = blockIdx.x;
    const int b    = blockIdx.y;
    const int w    = lane;
    const bool wok = (w < Ww);

    float acc[8] = {0.f,0.f,0.f,0.f,0.f,0.f,0.f,0.f};
    const size_t xbase = (size_t)b * Cc * Ll;

    for (int cc = 0; cc < 16; ++cc) {
        const int c = cs * 16 + cc;
        float xv[9];
#pragma unroll
        for (int dh = 0; dh < 3; ++dh) {
            const int hh = h + dh - 1;
            const bool hok = (hh >= 0) & (hh < Hh);
            const size_t rowb = xbase + (size_t)c * Ll + (size_t)(hh * Ww);
#pragma unroll
            for (int dw = 0; dw < 3; ++dw) {
                const int ww = w + dw - 1;
                const bool ok = hok & (ww >= 0) & (ww < Ww);
                xv[dh * 3 + dw] = ok ? ld<XB>(x, rowb + ww) : 0.0f;
            }
        }
        // Bt[(c*9+i)*16 + rh*8 + j]: uniform index -> scalar s_load, SGPR operand
        const float* bt = Bt + (size_t)(c * 9) * Rr + rh * 8;
#pragma unroll
        for (int i = 0; i < 9; ++i) {
#pragma unroll
            for (int j = 0; j < 8; ++j)
                acc[j] += bt[(size_t)i * Rr + j] * xv[i];
        }
    }

    // cross-wave reduction: 8 channel-slices -> tmp2[px][r]
#pragma unroll
    for (int j = 0; j < 8; ++j) part[cs][rh * 8 + j][lane] = acc[j];
    __syncthreads();
    {
        const int r  = tid >> 6;    // 0..15
        const int px = tid & 63;
        float s = 0.f;
#pragma unroll
        for (int s8 = 0; s8 < 8; ++s8) s += part[s8][r][px];
        tmp2[px][r] = s;            // stride 17 -> conflict-free
    }
    __syncthreads();

    // stage 2: wave wv emits output channels wv*16 .. +16
    float tv[Rr];
#pragma unroll
    for (int r = 0; r < Rr; ++r) tv[r] = tmp2[lane][r];

    const size_t obase = (size_t)b * Oo * Ll + (size_t)(h * Ww) + (size_t)w;
#pragma unroll
    for (int j = 0; j < 16; ++j) {
        const int o = wv * 16 + j;
        const float* Ao = Afp + (size_t)o * Rr;   // uniform -> s_load_dwordx16
        float s = 0.f;
#pragma unroll
        for (int r = 0; r < Rr; ++r) s += Ao[r] * tv[r];
        if (wok) out[obase + (size_t)o * Ll] = s;
    }
}

__global__ __launch_bounds__(1024, 8) void fused_big(
    const void* __restrict__ x,
    const float* __restrict__ Bt,
    const float* __restrict__ Afp,
    float* __restrict__ out)
{
    __shared__ float part[8][Rr][64];   // 32 KB
    __shared__ float tmp2[64][17];      // 4.3 KB
    if (detect_bf16(x)) main_body<true >(x, Bt, Afp, out, part, tmp2);
    else                main_body<false>(x, Bt, Afp, out, part, tmp2);
}

// ---- fallback (ws too small): slow but correct, no workspace.
__global__ __launch_bounds__(256) void fused_fallback(
    const void* __restrict__ x, const void* __restrict__ A,
    const void* __restrict__ Bm, float* __restrict__ out)
{
    const bool xb = detect_bf16(x);
    const bool ab = detect_bf16(A);
    const bool bb = detect_bf16(Bm);
    const int gid = blockIdx.x * 256 + threadIdx.x;
    const int b = gid / Ll;
    const int l = gid - b * Ll;
    const int h = l / Ww, w = l - h * Ww;
    float acc[Rr];
#pragma unroll
    for (int r = 0; r < Rr; ++r) acc[r] = 0.f;
    const size_t xbase = (size_t)b * Cc * Ll;
    for (int c = 0; c < Cc; ++c) {
        const size_t xc = xbase + (size_t)c * Ll;
        float xv[9];
#pragma unroll
        for (int dh = 0; dh < 3; ++dh) {
            const int hh = h + dh - 1;
            const bool hok = (hh >= 0) & (hh < Hh);
#pragma unroll
            for (int dw = 0; dw < 3; ++dw) {
                const int ww = w + dw - 1;
                const bool ok = hok & (ww >= 0) & (ww < Ww);
                const size_t idx = xc + (size_t)(hh * Ww + ww);
                xv[dh*3+dw] = ok ? (xb ? bf16_bits(((const unsigned short*)x)[idx])
                                       : ((const float*)x)[idx]) : 0.f;
            }
        }
#pragma unroll
        for (int r = 0; r < Rr; ++r) {
            const size_t bo = (size_t)r * KF + (size_t)c * 9;
            float s = acc[r];
#pragma unroll
            for (int i = 0; i < 9; ++i)
                s += (bb ? bf16_bits(((const unsigned short*)Bm)[bo+i])
                         : ((const float*)Bm)[bo+i]) * xv[i];
            acc[r] = s;
        }
    }
    const size_t obase = (size_t)b * Oo * Ll + (size_t)l;
    for (int o = 0; o < Oo; ++o) {
        float s = 0.f;
#pragma unroll
        for (int r = 0; r < Rr; ++r)
            s += (ab ? bf16_bits(((const unsigned short*)A)[o*Rr+r])
                     : ((const float*)A)[o*Rr+r]) * acc[r];
        out[obase + (size_t)o * Ll] = s;
    }
}

extern "C" void kernel_launch(void* const* d_in, const int* in_sizes, int n_in,
                              void* d_out, int out_size, void* d_ws, size_t ws_size,
                              hipStream_t stream) {
    const void* x  = d_in[0];
    const void* A  = d_in[1];
    const void* Bm = d_in[2];
    for (int i = 0; i < n_in && i < 3; ++i) {
        const int s = in_sizes[i];
        if      (s == Bn * Cc * Ll) x  = d_in[i];
        else if (s == Oo * Rr)      A  = d_in[i];
        else if (s == Rr * KF)      Bm = d_in[i];
    }
    float* out = (float*)d_out;

    const size_t need = (size_t)(KF * Rr + Oo * Rr) * sizeof(float);  // 90112 B
    if (ws_size >= need) {
        float* Bt  = (float*)d_ws;
        float* Afp = Bt + KF * Rr;
        prep_kernel<<<dim3((KF * Rr + 255) / 256), 256, 0, stream>>>(A, Bm, Bt, Afp);
        fused_big<<<dim3(Hh, Bn), 1024, 0, stream>>>(x, Bt, Afp, out);
    } else {
        fused_fallback<<<dim3((Bn * Ll) / 256), 256, 0, stream>>>(x, A, Bm, out);
    }
}